// Round 1
// baseline (192.422 us; speedup 1.0000x reference)
//
#include <hip/hip_runtime.h>
#include <math.h>

#define CC 512
#define HH 38
#define WW 63
#define HWSZ (HH * WW)
#define NROIS 1024
#define NP 49            // 7x7 pooled positions
#define STG_STRIDE 260   // floats per p-row: 256 ch + 4 pad; 260*4B = 1040B (16B aligned)

typedef float f32x4 __attribute__((ext_vector_type(4)));

static __device__ __forceinline__ f32x4 splat4(float v) {
    f32x4 r; r[0] = v; r[1] = v; r[2] = v; r[3] = v; return r;
}

// ---------------- LDS-tiled transpose: CHW (512, 2394) -> HWC (2394, 512) ----
__global__ __launch_bounds__(256) void transpose_tiled(
        const float* __restrict__ src, float* __restrict__ dst) {
    __shared__ float tile[64][65];
    int s0 = blockIdx.x * 64;
    int c0 = blockIdx.y * 64;
    int tx = threadIdx.x & 63;
    int ty = threadIdx.x >> 6;

#pragma unroll
    for (int k = 0; k < 16; ++k) {
        int c = ty * 16 + k;
        int s = s0 + tx;
        float v = (s < HWSZ) ? src[(c0 + c) * HWSZ + s] : 0.0f;
        tile[tx][c] = v;
    }
    __syncthreads();
#pragma unroll
    for (int k = 0; k < 16; ++k) {
        int s = ty * 16 + k;
        if (s0 + s < HWSZ)
            dst[(s0 + s) * CC + c0 + tx] = tile[s][tx];
    }
}

// ---------------- main kernel v6 ---------------------------------------------
// Block = 448 threads = 7 waves = HALF roi (256 channels). Wave w = one output
// row oy = w (perfectly balanced: every wave does exactly 28 samples). Lane l
// owns 4 consecutive channels c = h*256 + 4l -> every gather is a float4
// (16B/lane, 1KB/wave, fully coalesced): 4x fewer load instructions and 4x
// less address VALU than the scalar-channel v5, same bytes. Interp math on
// f32x4 packs into v_pk_* ops. Stage is p-major [49][260]: the per-output
// ds_write_b128 at (260*p + 4l) is the canonical contiguous pattern
// (conflict-free); flush does a transposed read (28 scalar ds_reads/thread,
// mild conflicts) and nontemporal float4 global stores so the 100MB
// write-once output doesn't thrash L2 against the gathers.
__global__ __launch_bounds__(448) void roi_pool_v6(
        const float* __restrict__ img,    // HWC (2394, 512)
        const float* __restrict__ rois,   // (N, 5)
        float* __restrict__ out) {        // (N, 512, 7, 7)
    __shared__ float stage[NP * STG_STRIDE];   // 50960 B

    int n = blockIdx.x >> 1;              // wave-uniform
    int h = blockIdx.x & 1;
    int t = threadIdx.x;
    int l = t & 63;
    int oy = t >> 6;                      // 0..6, wave-uniform

    const float* r = rois + n * 5;
    float x1n = (r[1] * 0.0625f) / 62.0f;
    float y1n = (r[2] * 0.0625f) / 37.0f;
    float x2n = (r[3] * 0.0625f) / 62.0f;
    float y2n = (r[4] * 0.0625f) / 37.0f;
    float ydn = y2n - y1n;
    float xdn = x2n - x1n;

    // lane's 4-channel base, in f32x4 units: channel (h*256 + 4l)
    const f32x4* img4 = (const f32x4*)img + (h << 6) + l;

    // x-side interpolation params (fully unrolled -> registers)
    float wxa[14];
    int   x0a[14], x1a[14];               // pre-scaled to f32x4 units (x * 128)
    int   vxm = 0;
#pragma unroll
    for (int ix = 0; ix < 14; ++ix) {
        float tt = (float)ix * (1.0f / 13.0f);
        float in_x = (x1n + tt * xdn) * 62.0f;
        if (in_x >= 0.0f && in_x <= 62.0f) vxm |= (1 << ix);
        float x0f = floorf(in_x);
        wxa[ix] = in_x - x0f;
        x0a[ix] = (int)fminf(fmaxf(x0f, 0.0f), 62.0f) * 128;
        x1a[ix] = (int)fminf(fmaxf(x0f + 1.0f, 0.0f), 62.0f) * 128;
    }

    f32x4 row[7];
#pragma unroll
    for (int ox = 0; ox < 7; ++ox) row[ox] = splat4(-INFINITY);

#pragma unroll 1                          // rolled: halves code size / live ranges
    for (int sy = 0; sy < 2; ++sy) {
        int iy = oy * 2 + sy;
        float tt = (float)iy * (1.0f / 13.0f);
        float in_y = (y1n + tt * ydn) * 37.0f;
        bool vy = (in_y >= 0.0f) && (in_y <= 37.0f);
        float y0f = floorf(in_y);
        float wy = in_y - y0f;
        int yy0 = (int)fminf(fmaxf(y0f, 0.0f), 37.0f);
        int yy1 = (int)fminf(fmaxf(y0f + 1.0f, 0.0f), 37.0f);
        int yb0 = yy0 * (WW * 128);       // f32x4 units per y-row
        int yb1 = yy1 * (WW * 128);

#pragma unroll
        for (int ox = 0; ox < 7; ++ox) {
#pragma unroll
            for (int sx = 0; sx < 2; ++sx) {
                int ix = ox * 2 + sx;
                f32x4 g00 = img4[yb0 + x0a[ix]];
                f32x4 g01 = img4[yb0 + x1a[ix]];
                f32x4 g10 = img4[yb1 + x0a[ix]];
                f32x4 g11 = img4[yb1 + x1a[ix]];
                float wx = wxa[ix];
                f32x4 top = g00 + (g01 - g00) * wx;
                f32x4 bot = g10 + (g11 - g10) * wx;
                f32x4 val = top + (bot - top) * wy;
                bool valid = vy && ((vxm >> ix) & 1);
                val = valid ? val : splat4(0.0f);
#pragma unroll
                for (int j = 0; j < 4; ++j)
                    row[ox][j] = fmaxf(row[ox][j], val[j]);
            }
        }
    }

    // stage: p-major, conflict-free ds_write_b128 (contiguous 1KB per wave)
#pragma unroll
    for (int ox = 0; ox < 7; ++ox) {
        int p = oy * 7 + ox;
        ((f32x4*)(stage + p * STG_STRIDE))[l] = row[ox];
    }

    __syncthreads();

    // flush: transpose-read LDS, dense nontemporal float4 stores.
    // half-roi region = 256*49 floats = 3136 float4 = 448 threads * 7 iters.
    f32x4* o4 = (f32x4*)(out + ((n << 9) + (h << 8)) * NP);
#pragma unroll
    for (int k = 0; k < 7; ++k) {
        int i = t + k * 448;
        int m = i << 2;
        f32x4 v;
#pragma unroll
        for (int j = 0; j < 4; ++j) {
            int mm = m + j;
            int ch = mm / 49;             // local channel 0..255
            int p  = mm - ch * 49;        // pooled position 0..48
            v[j] = stage[p * STG_STRIDE + ch];
        }
        __builtin_nontemporal_store(v, &o4[i]);
    }
}

// ---------------- fallback (ws too small): direct CHW gathers ----------------
__global__ __launch_bounds__(256) void roi_pool_chw(
        const float* __restrict__ img,    // CHW
        const float* __restrict__ rois,
        float* __restrict__ out) {
    __shared__ float stage[256 * NP];
    int n = blockIdx.x >> 1;
    int h = blockIdx.x & 1;
    int t = threadIdx.x;
    int c = (h << 8) + t;

    const float* r = rois + n * 5;
    float x1n = (r[1] * 0.0625f) / 62.0f;
    float y1n = (r[2] * 0.0625f) / 37.0f;
    float x2n = (r[3] * 0.0625f) / 62.0f;
    float y2n = (r[4] * 0.0625f) / 37.0f;
    float ydn = y2n - y1n;
    float xdn = x2n - x1n;

    const float* imgc = img + c * HWSZ;

    float wxa[14];
    int   x0a[14], x1a[14];
    int   vxm = 0;
#pragma unroll
    for (int ix = 0; ix < 14; ++ix) {
        float tt = (float)ix * (1.0f / 13.0f);
        float in_x = (x1n + tt * xdn) * 62.0f;
        if (in_x >= 0.0f && in_x <= 62.0f) vxm |= (1 << ix);
        float x0f = floorf(in_x);
        wxa[ix] = in_x - x0f;
        x0a[ix] = (int)fminf(fmaxf(x0f, 0.0f), 62.0f);
        x1a[ix] = (int)fminf(fmaxf(x0f + 1.0f, 0.0f), 62.0f);
    }

#pragma unroll
    for (int oy = 0; oy < 7; ++oy) {
        float row[7];
#pragma unroll
        for (int ox = 0; ox < 7; ++ox) row[ox] = -INFINITY;
#pragma unroll
        for (int sy = 0; sy < 2; ++sy) {
            int iy = oy * 2 + sy;
            float tt = (float)iy * (1.0f / 13.0f);
            float in_y = (y1n + tt * ydn) * 37.0f;
            bool vy = (in_y >= 0.0f) && (in_y <= 37.0f);
            float y0f = floorf(in_y);
            float wy = in_y - y0f;
            int yy0 = (int)fminf(fmaxf(y0f, 0.0f), 37.0f);
            int yy1 = (int)fminf(fmaxf(y0f + 1.0f, 0.0f), 37.0f);
            int yb0 = yy0 * WW;
            int yb1 = yy1 * WW;
#pragma unroll
            for (int ox = 0; ox < 7; ++ox) {
#pragma unroll
                for (int sx = 0; sx < 2; ++sx) {
                    int ix = ox * 2 + sx;
                    float g00 = imgc[yb0 + x0a[ix]];
                    float g01 = imgc[yb0 + x1a[ix]];
                    float g10 = imgc[yb1 + x0a[ix]];
                    float g11 = imgc[yb1 + x1a[ix]];
                    float wx = wxa[ix];
                    float top = g00 + (g01 - g00) * wx;
                    float bot = g10 + (g11 - g10) * wx;
                    float val = top + (bot - top) * wy;
                    bool valid = vy && ((vxm >> ix) & 1);
                    val = valid ? val : 0.0f;
                    row[ox] = fmaxf(row[ox], val);
                }
            }
        }
#pragma unroll
        for (int ox = 0; ox < 7; ++ox)
            stage[t * NP + oy * 7 + ox] = row[ox];
    }

    __syncthreads();
    const float4* s4 = (const float4*)stage;
    float4* o4 = (float4*)(out + ((n << 9) + (h << 8)) * NP);
    for (int i = t; i < (256 * NP) / 4; i += 256)
        o4[i] = s4[i];
}

extern "C" void kernel_launch(void* const* d_in, const int* in_sizes, int n_in,
                              void* d_out, int out_size, void* d_ws, size_t ws_size,
                              hipStream_t stream) {
    const float* bottom = (const float*)d_in[0];
    const float* rois   = (const float*)d_in[1];
    float* out = (float*)d_out;

    const size_t need = (size_t)CC * HWSZ * sizeof(float);  // ~4.9 MB
    if (ws_size >= need) {
        float* img = (float*)d_ws;
        dim3 tg((HWSZ + 63) / 64, CC / 64);   // 38 x 8
        transpose_tiled<<<tg, 256, 0, stream>>>(bottom, img);
        roi_pool_v6<<<NROIS * 2, 448, 0, stream>>>(img, rois, out);
    } else {
        roi_pool_chw<<<NROIS * 2, 256, 0, stream>>>(bottom, rois, out);
    }
}

// Round 2
// 162.506 us; speedup vs baseline: 1.1841x; 1.1841x over previous
//
#include <hip/hip_runtime.h>
#include <math.h>

#define CC 512
#define HH 38
#define WW 63
#define HWSZ (HH * WW)
#define NROIS 1024
#define NP 49            // 7x7 pooled positions

typedef float f32x4 __attribute__((ext_vector_type(4)));

static __device__ __forceinline__ f32x4 splat4(float v) {
    f32x4 r; r[0] = v; r[1] = v; r[2] = v; r[3] = v; return r;
}

// ---------------- LDS-tiled transpose: CHW (512, 2394) -> HWC (2394, 512) ----
__global__ __launch_bounds__(256) void transpose_tiled(
        const float* __restrict__ src, float* __restrict__ dst) {
    __shared__ float tile[64][65];
    int s0 = blockIdx.x * 64;
    int c0 = blockIdx.y * 64;
    int tx = threadIdx.x & 63;
    int ty = threadIdx.x >> 6;

#pragma unroll
    for (int k = 0; k < 16; ++k) {
        int c = ty * 16 + k;
        int s = s0 + tx;
        float v = (s < HWSZ) ? src[(c0 + c) * HWSZ + s] : 0.0f;
        tile[tx][c] = v;
    }
    __syncthreads();
#pragma unroll
    for (int k = 0; k < 16; ++k) {
        int s = ty * 16 + k;
        if (s0 + s < HWSZ)
            dst[(s0 + s) * CC + c0 + tx] = tile[s][tx];
    }
}

// ---------------- main kernel v7 ---------------------------------------------
// Block = 256 threads = 4 waves = QUARTER roi (128 ch = 32 float4 quads).
// Lane g = t&31 owns channels q*128 + 4g..4g+3 (one float4 gather = 16B/lane,
// 1KB/wave coalesced -> 3.5x fewer load instrs than v5 scalar). Slot s = t>>5
// in [0,8): one output row each; slot 7 idle (12.5% lane waste, but all 4
// waves run IDENTICAL instruction streams -> no v5-style 4row/3row barrier
// imbalance). Occupancy envelope restored vs v6: LDS 25088 B -> 6 blocks/CU,
// 4-wave blocks degrade gracefully with VGPR (no 7-wave-block cliff).
// Stage keeps v5's channel-major stride-49 FLOAT layout: 4 scalar ds_writes
// per output (bank = 4g+17jj+p -> 16 banks = 4-way on just 28 writes/thread,
// ~1.58x per m136) so the flush stays v5's proven LINEAR float4 copy: zero
// index math, zero read conflicts, dense nontemporal stores (write-once
// 100MB output kept out of L2's way).
__global__ __launch_bounds__(256) void roi_pool_v7(
        const float* __restrict__ img,    // HWC (2394, 512)
        const float* __restrict__ rois,   // (N, 5)
        float* __restrict__ out) {        // (N, 512, 7, 7)
    __shared__ float stage[128 * NP];     // 25088 B

    int n = blockIdx.x >> 2;              // wave-uniform
    int q = blockIdx.x & 3;
    int t = threadIdx.x;
    int g = t & 31;                       // channel-quad within quarter
    int s = t >> 5;                       // row slot 0..7 (slot 7 idle)

    const float* r = rois + n * 5;
    float x1n = (r[1] * 0.0625f) / 62.0f;
    float y1n = (r[2] * 0.0625f) / 37.0f;
    float x2n = (r[3] * 0.0625f) / 62.0f;
    float y2n = (r[4] * 0.0625f) / 37.0f;
    float ydn = y2n - y1n;
    float xdn = x2n - x1n;

    if (s < 7) {
        int oy = s;
        // lane's 4-channel base in f32x4 units
        const f32x4* img4 = (const f32x4*)img + (q << 5) + g;

        // y-params for this row's two sample rows (static-indexed arrays)
        float wy[2]; int ybA[2], ybB[2]; bool vy[2];
#pragma unroll
        for (int sy = 0; sy < 2; ++sy) {
            int iy = oy * 2 + sy;
            float tty = (float)iy * (1.0f / 13.0f);
            float in_y = (y1n + tty * ydn) * 37.0f;
            vy[sy] = (in_y >= 0.0f) && (in_y <= 37.0f);
            float y0f = floorf(in_y);
            wy[sy] = in_y - y0f;
            ybA[sy] = (int)fminf(fmaxf(y0f, 0.0f), 37.0f) * (WW * (CC / 4));
            ybB[sy] = (int)fminf(fmaxf(y0f + 1.0f, 0.0f), 37.0f) * (WW * (CC / 4));
        }

        int sbase = g * (4 * NP) + oy * 7;   // stage float base for channel 4g

#pragma unroll
        for (int ox = 0; ox < 7; ++ox) {
            f32x4 acc = splat4(-INFINITY);
#pragma unroll
            for (int sx = 0; sx < 2; ++sx) {
                int ixx = ox * 2 + sx;
                float ttx = (float)ixx * (1.0f / 13.0f);
                float in_x = (x1n + ttx * xdn) * 62.0f;
                bool vx = (in_x >= 0.0f) && (in_x <= 62.0f);
                float x0f = floorf(in_x);
                float wx = in_x - x0f;
                int xq0 = (int)fminf(fmaxf(x0f, 0.0f), 62.0f) << 7;        // * CC/4
                int xq1 = (int)fminf(fmaxf(x0f + 1.0f, 0.0f), 62.0f) << 7;
#pragma unroll
                for (int sy = 0; sy < 2; ++sy) {
                    f32x4 g00 = img4[ybA[sy] + xq0];
                    f32x4 g01 = img4[ybA[sy] + xq1];
                    f32x4 g10 = img4[ybB[sy] + xq0];
                    f32x4 g11 = img4[ybB[sy] + xq1];
                    f32x4 top = g00 + (g01 - g00) * wx;
                    f32x4 bot = g10 + (g11 - g10) * wx;
                    f32x4 val = top + (bot - top) * wy[sy];
                    bool valid = vx && vy[sy];
                    val = valid ? val : splat4(0.0f);
#pragma unroll
                    for (int j = 0; j < 4; ++j)
                        acc[j] = fmaxf(acc[j], val[j]);
                }
            }
            // 4 scalar stage writes: channels 4g..4g+3 at pooled pos oy*7+ox.
            // Compile-time byte offsets (196*jj) fold into ds_write offset imm.
            stage[sbase + ox         ] = acc[0];
            stage[sbase + ox + NP    ] = acc[1];
            stage[sbase + ox + 2 * NP] = acc[2];
            stage[sbase + ox + 3 * NP] = acc[3];
        }
    }

    __syncthreads();

    // linear flush: stage float layout == output layout for this quarter.
    // 1568 float4, dense, conflict-free reads, nontemporal stores.
    const f32x4* s4 = (const f32x4*)stage;
    f32x4* o4 = (f32x4*)(out + ((n << 9) + (q << 7)) * NP);
    for (int i = t; i < (128 * NP) / 4; i += 256)
        __builtin_nontemporal_store(s4[i], &o4[i]);
}

// ---------------- fallback (ws too small): direct CHW gathers ----------------
__global__ __launch_bounds__(256) void roi_pool_chw(
        const float* __restrict__ img,    // CHW
        const float* __restrict__ rois,
        float* __restrict__ out) {
    __shared__ float stage[256 * NP];
    int n = blockIdx.x >> 1;
    int h = blockIdx.x & 1;
    int t = threadIdx.x;
    int c = (h << 8) + t;

    const float* r = rois + n * 5;
    float x1n = (r[1] * 0.0625f) / 62.0f;
    float y1n = (r[2] * 0.0625f) / 37.0f;
    float x2n = (r[3] * 0.0625f) / 62.0f;
    float y2n = (r[4] * 0.0625f) / 37.0f;
    float ydn = y2n - y1n;
    float xdn = x2n - x1n;

    const float* imgc = img + c * HWSZ;

    float wxa[14];
    int   x0a[14], x1a[14];
    int   vxm = 0;
#pragma unroll
    for (int ix = 0; ix < 14; ++ix) {
        float tt = (float)ix * (1.0f / 13.0f);
        float in_x = (x1n + tt * xdn) * 62.0f;
        if (in_x >= 0.0f && in_x <= 62.0f) vxm |= (1 << ix);
        float x0f = floorf(in_x);
        wxa[ix] = in_x - x0f;
        x0a[ix] = (int)fminf(fmaxf(x0f, 0.0f), 62.0f);
        x1a[ix] = (int)fminf(fmaxf(x0f + 1.0f, 0.0f), 62.0f);
    }

#pragma unroll
    for (int oy = 0; oy < 7; ++oy) {
        float row[7];
#pragma unroll
        for (int ox = 0; ox < 7; ++ox) row[ox] = -INFINITY;
#pragma unroll
        for (int sy = 0; sy < 2; ++sy) {
            int iy = oy * 2 + sy;
            float tt = (float)iy * (1.0f / 13.0f);
            float in_y = (y1n + tt * ydn) * 37.0f;
            bool vy = (in_y >= 0.0f) && (in_y <= 37.0f);
            float y0f = floorf(in_y);
            float wy = in_y - y0f;
            int yy0 = (int)fminf(fmaxf(y0f, 0.0f), 37.0f);
            int yy1 = (int)fminf(fmaxf(y0f + 1.0f, 0.0f), 37.0f);
            int yb0 = yy0 * WW;
            int yb1 = yy1 * WW;
#pragma unroll
            for (int ox = 0; ox < 7; ++ox) {
#pragma unroll
                for (int sx = 0; sx < 2; ++sx) {
                    int ix = ox * 2 + sx;
                    float g00 = imgc[yb0 + x0a[ix]];
                    float g01 = imgc[yb0 + x1a[ix]];
                    float g10 = imgc[yb1 + x0a[ix]];
                    float g11 = imgc[yb1 + x1a[ix]];
                    float wx = wxa[ix];
                    float top = g00 + (g01 - g00) * wx;
                    float bot = g10 + (g11 - g10) * wx;
                    float val = top + (bot - top) * wy;
                    bool valid = vy && ((vxm >> ix) & 1);
                    val = valid ? val : 0.0f;
                    row[ox] = fmaxf(row[ox], val);
                }
            }
        }
#pragma unroll
        for (int ox = 0; ox < 7; ++ox)
            stage[t * NP + oy * 7 + ox] = row[ox];
    }

    __syncthreads();
    const float4* s4 = (const float4*)stage;
    float4* o4 = (float4*)(out + ((n << 9) + (h << 8)) * NP);
    for (int i = t; i < (256 * NP) / 4; i += 256)
        o4[i] = s4[i];
}

extern "C" void kernel_launch(void* const* d_in, const int* in_sizes, int n_in,
                              void* d_out, int out_size, void* d_ws, size_t ws_size,
                              hipStream_t stream) {
    const float* bottom = (const float*)d_in[0];
    const float* rois   = (const float*)d_in[1];
    float* out = (float*)d_out;

    const size_t need = (size_t)CC * HWSZ * sizeof(float);  // ~4.9 MB
    if (ws_size >= need) {
        float* img = (float*)d_ws;
        dim3 tg((HWSZ + 63) / 64, CC / 64);   // 38 x 8
        transpose_tiled<<<tg, 256, 0, stream>>>(bottom, img);
        roi_pool_v7<<<NROIS * 4, 256, 0, stream>>>(img, rois, out);
    } else {
        roi_pool_chw<<<NROIS * 2, 256, 0, stream>>>(bottom, rois, out);
    }
}